// Round 1
// baseline (102.990 us; speedup 1.0000x reference)
//
#include <hip/hip_runtime.h>
#include <math.h>

// Problem constants (from reference)
#define BB 2
#define CC 8
#define DD 64
#define HH 160
#define WW 160
#define SS (DD*HH*WW)            // 1,638,400 voxels per sample per channel
#define NVOX (BB*SS)             // 3,276,800 total voxels
#define THREADS 256
#define GPT 2                    // float4 groups per thread
#define BLOCKS_PER_SAMPLE (SS/(THREADS*4*GPT))   // 800
#define NBLOCKS (BB*BLOCKS_PER_SAMPLE)           // 1600

__device__ __forceinline__ float f4c(const float4& v, int j) {
    return j==0 ? v.x : (j==1 ? v.y : (j==2 ? v.z : v.w));
}
__device__ __forceinline__ int u4c(const uchar4& v, int j) {
    return j==0 ? (int)v.x : (j==1 ? (int)v.y : (j==2 ? (int)v.z : (int)v.w));
}

// Pass A: read target (one-hot), write per-voxel label byte, accumulate counts[b][c].
__global__ __launch_bounds__(THREADS)
void pass_label(const float* __restrict__ tgt,
                unsigned char* __restrict__ labels,
                unsigned int* __restrict__ counts) {
    __shared__ unsigned int scnt[CC];
    const int tid = threadIdx.x;
    if (tid < CC) scnt[tid] = 0u;
    __syncthreads();

    const int b   = blockIdx.x / BLOCKS_PER_SAMPLE;
    const int blk = blockIdx.x % BLOCKS_PER_SAMPLE;
    const int S4  = SS / 4;
    const float4* base = (const float4*)(tgt + (size_t)b * CC * SS);
    uchar4* lab4 = (uchar4*)labels + (size_t)b * S4;

    for (int it = 0; it < GPT; ++it) {
        const int g = blk * (THREADS * GPT) + it * THREADS + tid;
        float4 v[CC];
        #pragma unroll
        for (int c = 0; c < CC; ++c) v[c] = base[(size_t)c * S4 + g];

        int l0 = 0, l1 = 0, l2 = 0, l3 = 0;
        #pragma unroll
        for (int c = 1; c < CC; ++c) {
            if (v[c].x > 0.5f) l0 = c;
            if (v[c].y > 0.5f) l1 = c;
            if (v[c].z > 0.5f) l2 = c;
            if (v[c].w > 0.5f) l3 = c;
        }
        uchar4 L;
        L.x = (unsigned char)l0; L.y = (unsigned char)l1;
        L.z = (unsigned char)l2; L.w = (unsigned char)l3;
        lab4[g] = L;
        atomicAdd(&scnt[l0], 1u);
        atomicAdd(&scnt[l1], 1u);
        atomicAdd(&scnt[l2], 1u);
        atomicAdd(&scnt[l3], 1u);
    }
    __syncthreads();
    if (tid < CC) atomicAdd(&counts[b * CC + tid], scnt[tid]);
}

// Pass B: read net_output + labels, compute CE sum and per-(b,c) seg_vol / intersect.
__global__ __launch_bounds__(THREADS)
void pass_main(const float* __restrict__ net,
               const unsigned char* __restrict__ labels,
               const unsigned int* __restrict__ counts,
               float* __restrict__ seg,
               float* __restrict__ inter,
               float* __restrict__ ce_sum) {
    __shared__ float s_present[CC];
    __shared__ float s_logpad;
    __shared__ int   s_haspad;
    __shared__ float s_red[2 * CC + 1];   // seg[8], inter[8], ce

    const int tid = threadIdx.x;
    const int b   = blockIdx.x / BLOCKS_PER_SAMPLE;
    const int blk = blockIdx.x % BLOCKS_PER_SAMPLE;

    if (tid == 0) {
        int n0 = 0, n1 = 0;
        for (int c = 0; c < CC; ++c) {
            n0 += (counts[c] > 0u);
            n1 += (counts[CC + c] > 0u);
        }
        const int maxn = n0 > n1 ? n0 : n1;
        const int nb   = (b == 0) ? n0 : n1;
        const int pad  = maxn - nb;
        s_haspad = (pad > 0);
        s_logpad = (pad > 0) ? logf((float)pad) : 0.0f;
    }
    if (tid < CC) s_present[tid] = (counts[b * CC + tid] > 0u) ? 1.0f : 0.0f;
    if (tid < 2 * CC + 1) s_red[tid] = 0.0f;
    __syncthreads();

    float pr[CC];
    #pragma unroll
    for (int c = 0; c < CC; ++c) pr[c] = s_present[c];
    const float logpad = s_logpad;
    const int   haspad = s_haspad;

    float segA[CC];
    float intA[CC];
    #pragma unroll
    for (int c = 0; c < CC; ++c) { segA[c] = 0.0f; intA[c] = 0.0f; }
    float ceA = 0.0f;

    const int S4 = SS / 4;
    const float4* base = (const float4*)(net + (size_t)b * CC * SS);
    const uchar4* lab4 = (const uchar4*)labels + (size_t)b * S4;

    for (int it = 0; it < GPT; ++it) {
        const int g = blk * (THREADS * GPT) + it * THREADS + tid;
        float4 v[CC];
        #pragma unroll
        for (int c = 0; c < CC; ++c) v[c] = base[(size_t)c * S4 + g];
        const uchar4 L = lab4[g];

        #pragma unroll
        for (int j = 0; j < 4; ++j) {
            const int lab = u4c(L, j);
            float m[CC];
            m[0] = f4c(v[0], j);
            float bg = 0.0f;
            #pragma unroll
            for (int c = 1; c < CC; ++c) {
                const float x = f4c(v[c], j);
                m[c] = x;
                bg += (1.0f - pr[c]) * x;       // absent foreground folds into bg
            }
            m[0] += bg;

            float mx = -3.0e38f;
            #pragma unroll
            for (int c = 0; c < CC; ++c)
                mx = fmaxf(mx, (pr[c] > 0.0f) ? m[c] : -3.0e38f);

            float e[CC];
            float se = 0.0f;
            #pragma unroll
            for (int c = 0; c < CC; ++c) {
                e[c] = pr[c] * expf(m[c] - mx);
                se += e[c];
            }
            const float lse_p = mx + logf(se);
            const float inv   = 1.0f / se;

            float mlab = 0.0f;
            #pragma unroll
            for (int c = 0; c < CC; ++c) {
                const float p = e[c] * inv;
                segA[c] += p;
                const bool isl = (lab == c);
                if (isl) { intA[c] += p; mlab = m[c]; }
            }

            float lse = lse_p;
            if (haspad) {
                const float a = lse_p, bq = logpad;
                lse = fmaxf(a, bq) + log1pf(expf(-fabsf(a - bq)));
            }
            ceA += lse - mlab;
        }
    }

    // wave-level reduction (64 lanes) then shared accumulation
    #pragma unroll
    for (int off = 32; off > 0; off >>= 1) {
        #pragma unroll
        for (int c = 0; c < CC; ++c) {
            segA[c] += __shfl_down(segA[c], off, 64);
            intA[c] += __shfl_down(intA[c], off, 64);
        }
        ceA += __shfl_down(ceA, off, 64);
    }
    if ((tid & 63) == 0) {
        #pragma unroll
        for (int c = 0; c < CC; ++c) {
            atomicAdd(&s_red[c],      segA[c]);
            atomicAdd(&s_red[CC + c], intA[c]);
        }
        atomicAdd(&s_red[2 * CC], ceA);
    }
    __syncthreads();
    if (tid < CC) {
        atomicAdd(&seg[b * CC + tid],   s_red[tid]);
        atomicAdd(&inter[b * CC + tid], s_red[CC + tid]);
    }
    if (tid == 2 * CC) atomicAdd(ce_sum, s_red[2 * CC]);
}

__global__ void finalize(const unsigned int* __restrict__ counts,
                         const float* __restrict__ seg,
                         const float* __restrict__ inter,
                         const float* __restrict__ ce_sum,
                         float* __restrict__ out) {
    if (threadIdx.x == 0 && blockIdx.x == 0) {
        const float ce = ce_sum[0] / (float)NVOX;
        float dc = 0.0f;
        for (int b = 0; b < BB; ++b) {
            int nb = 0;
            float acc = 0.0f;
            for (int c = 0; c < CC; ++c) {
                const unsigned int cnt = counts[b * CC + c];
                if (cnt > 0u) {
                    ++nb;
                    const float R = (float)cnt;
                    const float Sg = seg[b * CC + c];
                    const float I = inter[b * CC + c];
                    acc += 2.0f * I / (R + Sg + 1e-5f);
                }
            }
            dc += 1.0f - acc / (float)nb;
        }
        dc /= (float)BB;
        out[0] = 0.5f * ce + 0.5f * dc;
    }
}

extern "C" void kernel_launch(void* const* d_in, const int* in_sizes, int n_in,
                              void* d_out, int out_size, void* d_ws, size_t ws_size,
                              hipStream_t stream) {
    const float* net = (const float*)d_in[0];
    const float* tgt = (const float*)d_in[1];
    float* out = (float*)d_out;

    // workspace layout
    unsigned int* counts = (unsigned int*)d_ws;                       // 16 u32
    float* seg   = (float*)((char*)d_ws + 64);                        // 16 f32
    float* inter = (float*)((char*)d_ws + 128);                       // 16 f32
    float* ce    = (float*)((char*)d_ws + 192);                       // 1 f32
    unsigned char* labels = (unsigned char*)d_ws + 256;               // NVOX bytes

    hipMemsetAsync(d_ws, 0, 256, stream);
    pass_label<<<NBLOCKS, THREADS, 0, stream>>>(tgt, labels, counts);
    pass_main<<<NBLOCKS, THREADS, 0, stream>>>(net, labels, counts, seg, inter, ce);
    finalize<<<1, 64, 0, stream>>>(counts, seg, inter, ce, out);
}

// Round 2
// 102.325 us; speedup vs baseline: 1.0065x; 1.0065x over previous
//
#include <hip/hip_runtime.h>
#include <math.h>

// Problem constants (from reference)
#define BB 2
#define CC 8
#define DD 64
#define HH 160
#define WW 160
#define SS (DD*HH*WW)            // 1,638,400 voxels per sample per channel
#define NVOX (BB*SS)             // 3,276,800 total voxels
#define THREADS 256
#define GPT 2                    // float4 groups per thread
#define BLOCKS_PER_SAMPLE (SS/(THREADS*4*GPT))   // 800
#define NBLOCKS (BB*BLOCKS_PER_SAMPLE)           // 1600

#define L2E 1.4426950408889634f
#define LN2 0.6931471805599453f

__device__ __forceinline__ float f4c(const float4& v, int j) {
    return j==0 ? v.x : (j==1 ? v.y : (j==2 ? v.z : v.w));
}
__device__ __forceinline__ int u4c(const uchar4& v, int j) {
    return j==0 ? (int)v.x : (j==1 ? (int)v.y : (j==2 ? (int)v.z : (int)v.w));
}

// Pass A: read target (one-hot), write per-voxel label byte, accumulate counts[b][c].
__global__ __launch_bounds__(THREADS)
void pass_label(const float* __restrict__ tgt,
                unsigned char* __restrict__ labels,
                unsigned int* __restrict__ counts) {
    __shared__ unsigned int scnt[CC];
    const int tid = threadIdx.x;
    if (tid < CC) scnt[tid] = 0u;
    __syncthreads();

    const int b   = blockIdx.x / BLOCKS_PER_SAMPLE;
    const int blk = blockIdx.x % BLOCKS_PER_SAMPLE;
    const int S4  = SS / 4;
    const float4* base = (const float4*)(tgt + (size_t)b * CC * SS);
    uchar4* lab4 = (uchar4*)labels + (size_t)b * S4;

    for (int it = 0; it < GPT; ++it) {
        const int g = blk * (THREADS * GPT) + it * THREADS + tid;
        float4 v[CC];
        #pragma unroll
        for (int c = 0; c < CC; ++c) v[c] = base[(size_t)c * S4 + g];

        int l0 = 0, l1 = 0, l2 = 0, l3 = 0;
        #pragma unroll
        for (int c = 1; c < CC; ++c) {
            if (v[c].x > 0.5f) l0 = c;
            if (v[c].y > 0.5f) l1 = c;
            if (v[c].z > 0.5f) l2 = c;
            if (v[c].w > 0.5f) l3 = c;
        }
        uchar4 L;
        L.x = (unsigned char)l0; L.y = (unsigned char)l1;
        L.z = (unsigned char)l2; L.w = (unsigned char)l3;
        lab4[g] = L;
        atomicAdd(&scnt[l0], 1u);
        atomicAdd(&scnt[l1], 1u);
        atomicAdd(&scnt[l2], 1u);
        atomicAdd(&scnt[l3], 1u);
    }
    __syncthreads();
    if (tid < CC) atomicAdd(&counts[b * CC + tid], scnt[tid]);
}

// Pass B: read net_output + labels, compute CE sum and per-(b,c) seg_vol / intersect.
// Fast-math raw transcendentals; presence mask folded into exp2 bias; padding
// channels (logit 0) folded analytically: lse = ln(sum_present exp(m) + pad).
__global__ __launch_bounds__(THREADS)
void pass_main(const float* __restrict__ net,
               const unsigned char* __restrict__ labels,
               const unsigned int* __restrict__ counts,
               float* __restrict__ seg,
               float* __restrict__ inter,
               float* __restrict__ ce_sum) {
    __shared__ float s_ab[CC];      // 1 if absent else 0 (fold coefficient)
    __shared__ float s_bias[CC];    // 0 if present else -2048 (exp2 domain)
    __shared__ float s_padf;        // number of zero-logit padding channels
    __shared__ float s_red[2 * CC + 1];   // seg[8], inter[8], ce

    const int tid = threadIdx.x;
    const int b   = blockIdx.x / BLOCKS_PER_SAMPLE;
    const int blk = blockIdx.x % BLOCKS_PER_SAMPLE;

    if (tid == 0) {
        int n0 = 0, n1 = 0;
        for (int c = 0; c < CC; ++c) {
            n0 += (counts[c] > 0u);
            n1 += (counts[CC + c] > 0u);
        }
        const int maxn = n0 > n1 ? n0 : n1;
        const int nb   = (b == 0) ? n0 : n1;
        s_padf = (float)(maxn - nb);
    }
    if (tid < CC) {
        const bool present = counts[b * CC + tid] > 0u;
        s_ab[tid]   = present ? 0.0f : 1.0f;
        s_bias[tid] = present ? 0.0f : -2048.0f;
    }
    if (tid < 2 * CC + 1) s_red[tid] = 0.0f;
    __syncthreads();

    float ab[CC], bias[CC];
    #pragma unroll
    for (int c = 0; c < CC; ++c) { ab[c] = s_ab[c]; bias[c] = s_bias[c]; }
    const float padf = s_padf;

    float segA[CC];
    float intA[CC];
    #pragma unroll
    for (int c = 0; c < CC; ++c) { segA[c] = 0.0f; intA[c] = 0.0f; }
    float ceA = 0.0f;

    const int S4 = SS / 4;
    const float4* base = (const float4*)(net + (size_t)b * CC * SS);
    const uchar4* lab4 = (const uchar4*)labels + (size_t)b * S4;

    for (int it = 0; it < GPT; ++it) {
        const int g = blk * (THREADS * GPT) + it * THREADS + tid;
        float4 v[CC];
        #pragma unroll
        for (int c = 0; c < CC; ++c) v[c] = base[(size_t)c * S4 + g];
        const uchar4 L = lab4[g];

        #pragma unroll
        for (int j = 0; j < 4; ++j) {
            const int lab = u4c(L, j);
            float m[CC];
            m[0] = f4c(v[0], j);
            float fold = 0.0f;
            #pragma unroll
            for (int c = 1; c < CC; ++c) {
                const float x = f4c(v[c], j);
                m[c] = x;
                fold = fmaf(ab[c], x, fold);    // absent foreground -> bg
            }
            m[0] += fold;

            // e[c] = present ? exp(m[c]) : 0   (bias -2048 underflows exp2 to 0)
            float e[CC];
            float se = padf;                    // zero-logit padding: exp(0)*pad
            #pragma unroll
            for (int c = 0; c < CC; ++c) {
                e[c] = __builtin_amdgcn_exp2f(fmaf(m[c], L2E, bias[c]));
                se += e[c];
            }
            const float lse = LN2 * __builtin_amdgcn_logf(se);

            const float sp = se - padf;         // present-only sum (softmax denom)
            float inv = __builtin_amdgcn_rcpf(sp);
            inv = inv * (2.0f - sp * inv);      // 1 Newton step

            float mlab = 0.0f;
            #pragma unroll
            for (int c = 0; c < CC; ++c) {
                const float p = e[c] * inv;
                segA[c] += p;
                const bool isl = (lab == c);
                intA[c] += isl ? p : 0.0f;
                mlab     = isl ? m[c] : mlab;
            }
            ceA += lse - mlab;
        }
    }

    // wave-level reduction (64 lanes) then shared accumulation
    #pragma unroll
    for (int off = 32; off > 0; off >>= 1) {
        #pragma unroll
        for (int c = 0; c < CC; ++c) {
            segA[c] += __shfl_down(segA[c], off, 64);
            intA[c] += __shfl_down(intA[c], off, 64);
        }
        ceA += __shfl_down(ceA, off, 64);
    }
    if ((tid & 63) == 0) {
        #pragma unroll
        for (int c = 0; c < CC; ++c) {
            atomicAdd(&s_red[c],      segA[c]);
            atomicAdd(&s_red[CC + c], intA[c]);
        }
        atomicAdd(&s_red[2 * CC], ceA);
    }
    __syncthreads();
    if (tid < CC) {
        atomicAdd(&seg[b * CC + tid],   s_red[tid]);
        atomicAdd(&inter[b * CC + tid], s_red[CC + tid]);
    }
    if (tid == 2 * CC) atomicAdd(ce_sum, s_red[2 * CC]);
}

__global__ void finalize(const unsigned int* __restrict__ counts,
                         const float* __restrict__ seg,
                         const float* __restrict__ inter,
                         const float* __restrict__ ce_sum,
                         float* __restrict__ out) {
    if (threadIdx.x == 0 && blockIdx.x == 0) {
        const float ce = ce_sum[0] / (float)NVOX;
        float dc = 0.0f;
        for (int b = 0; b < BB; ++b) {
            int nb = 0;
            float acc = 0.0f;
            for (int c = 0; c < CC; ++c) {
                const unsigned int cnt = counts[b * CC + c];
                if (cnt > 0u) {
                    ++nb;
                    const float R = (float)cnt;
                    const float Sg = seg[b * CC + c];
                    const float I = inter[b * CC + c];
                    acc += 2.0f * I / (R + Sg + 1e-5f);
                }
            }
            dc += 1.0f - acc / (float)nb;
        }
        dc /= (float)BB;
        out[0] = 0.5f * ce + 0.5f * dc;
    }
}

extern "C" void kernel_launch(void* const* d_in, const int* in_sizes, int n_in,
                              void* d_out, int out_size, void* d_ws, size_t ws_size,
                              hipStream_t stream) {
    const float* net = (const float*)d_in[0];
    const float* tgt = (const float*)d_in[1];
    float* out = (float*)d_out;

    // workspace layout
    unsigned int* counts = (unsigned int*)d_ws;                       // 16 u32
    float* seg   = (float*)((char*)d_ws + 64);                        // 16 f32
    float* inter = (float*)((char*)d_ws + 128);                       // 16 f32
    float* ce    = (float*)((char*)d_ws + 192);                       // 1 f32
    unsigned char* labels = (unsigned char*)d_ws + 256;               // NVOX bytes

    hipMemsetAsync(d_ws, 0, 256, stream);
    pass_label<<<NBLOCKS, THREADS, 0, stream>>>(tgt, labels, counts);
    pass_main<<<NBLOCKS, THREADS, 0, stream>>>(net, labels, counts, seg, inter, ce);
    finalize<<<1, 64, 0, stream>>>(counts, seg, inter, ce, out);
}

// Round 3
// 48.038 us; speedup vs baseline: 2.1439x; 2.1301x over previous
//
#include <hip/hip_runtime.h>
#include <math.h>

// Problem constants (from reference)
#define BB 2
#define CC 8
#define DD 64
#define HH 160
#define WW 160
#define SS (DD*HH*WW)            // 1,638,400 voxels per sample per channel
#define NVOX (BB*SS)             // 3,276,800 total voxels
#define THREADS 256
#define GPT 2                    // float4 groups per thread
#define BLOCKS_PER_SAMPLE (SS/(THREADS*4*GPT))   // 800
#define NBLOCKS (BB*BLOCKS_PER_SAMPLE)           // 1600

#define L2E 1.4426950408889634f
#define LN2 0.6931471805599453f

__device__ __forceinline__ float f4c(const float4& v, int j) {
    return j==0 ? v.x : (j==1 ? v.y : (j==2 ? v.z : v.w));
}
__device__ __forceinline__ int u4c(const uchar4& v, int j) {
    return j==0 ? (int)v.x : (j==1 ? (int)v.y : (j==2 ? (int)v.z : (int)v.w));
}

// Pass A: read target (one-hot), write per-voxel label byte, per-block count
// partials (NO contended global atomics).
__global__ __launch_bounds__(THREADS)
void pass_label(const float* __restrict__ tgt,
                unsigned char* __restrict__ labels,
                unsigned int* __restrict__ cnt_part) {
    __shared__ unsigned int scnt[CC];
    const int tid = threadIdx.x;
    if (tid < CC) scnt[tid] = 0u;
    __syncthreads();

    const int b   = blockIdx.x / BLOCKS_PER_SAMPLE;
    const int blk = blockIdx.x % BLOCKS_PER_SAMPLE;
    const int S4  = SS / 4;
    const float4* base = (const float4*)(tgt + (size_t)b * CC * SS);
    uchar4* lab4 = (uchar4*)labels + (size_t)b * S4;

    for (int it = 0; it < GPT; ++it) {
        const int g = blk * (THREADS * GPT) + it * THREADS + tid;
        float4 v[CC];
        #pragma unroll
        for (int c = 0; c < CC; ++c) v[c] = base[(size_t)c * S4 + g];

        int l0 = 0, l1 = 0, l2 = 0, l3 = 0;
        #pragma unroll
        for (int c = 1; c < CC; ++c) {
            if (v[c].x > 0.5f) l0 = c;
            if (v[c].y > 0.5f) l1 = c;
            if (v[c].z > 0.5f) l2 = c;
            if (v[c].w > 0.5f) l3 = c;
        }
        uchar4 L;
        L.x = (unsigned char)l0; L.y = (unsigned char)l1;
        L.z = (unsigned char)l2; L.w = (unsigned char)l3;
        lab4[g] = L;
        atomicAdd(&scnt[l0], 1u);   // LDS atomics: uncontended across blocks
        atomicAdd(&scnt[l1], 1u);
        atomicAdd(&scnt[l2], 1u);
        atomicAdd(&scnt[l3], 1u);
    }
    __syncthreads();
    if (tid < CC) cnt_part[tid * NBLOCKS + blockIdx.x] = scnt[tid];
}

// Reduce per-block count partials -> counts[2][8], plus derived float params:
// fpar[0..7]=absent(b0), fpar[8..15]=absent(b1), fpar[16]=pad(b0), fpar[17]=pad(b1)
__global__ __launch_bounds__(512)
void reduce_counts(const unsigned int* __restrict__ cnt_part,
                   unsigned int* __restrict__ counts,
                   float* __restrict__ fpar) {
    __shared__ unsigned int sc[2 * CC];
    const int tid = threadIdx.x;
    const int w = tid >> 6, lane = tid & 63;
    unsigned int a0 = 0, a1 = 0;
    const unsigned int* col = cnt_part + w * NBLOCKS;
    #pragma unroll
    for (int k = 0; k < NBLOCKS / 64; ++k) {
        const int blk = lane + (k << 6);
        const unsigned int v = col[blk];
        if (blk < BLOCKS_PER_SAMPLE) a0 += v; else a1 += v;
    }
    #pragma unroll
    for (int off = 32; off > 0; off >>= 1) {
        a0 += __shfl_down(a0, off, 64);
        a1 += __shfl_down(a1, off, 64);
    }
    if (lane == 0) { sc[w] = a0; sc[CC + w] = a1; counts[w] = a0; counts[CC + w] = a1; }
    __syncthreads();
    if (tid == 0) {
        int n0 = 0, n1 = 0;
        for (int c = 0; c < CC; ++c) { n0 += (sc[c] > 0u); n1 += (sc[CC + c] > 0u); }
        const int maxn = n0 > n1 ? n0 : n1;
        for (int c = 0; c < CC; ++c) {
            fpar[c]      = (sc[c]      > 0u) ? 0.0f : 1.0f;
            fpar[CC + c] = (sc[CC + c] > 0u) ? 0.0f : 1.0f;
        }
        fpar[16] = (float)(maxn - n0);
        fpar[17] = (float)(maxn - n1);
    }
}

// Pass B: read net_output + labels; per-block partials for seg[8], inter[8], ce.
__global__ __launch_bounds__(THREADS)
void pass_main(const float* __restrict__ net,
               const unsigned char* __restrict__ labels,
               const float* __restrict__ fpar,
               float* __restrict__ part) {
    __shared__ float s_ab[CC];
    __shared__ float s_padf;
    __shared__ float s_red[2 * CC + 1];   // seg[8], inter[8], ce

    const int tid = threadIdx.x;
    const int b   = blockIdx.x / BLOCKS_PER_SAMPLE;
    const int blk = blockIdx.x % BLOCKS_PER_SAMPLE;

    if (tid < CC) s_ab[tid] = fpar[b * CC + tid];
    if (tid == CC) s_padf = fpar[2 * CC + b];
    if (tid < 2 * CC + 1) s_red[tid] = 0.0f;
    __syncthreads();

    float ab[CC], bias[CC];
    #pragma unroll
    for (int c = 0; c < CC; ++c) { ab[c] = s_ab[c]; bias[c] = -2048.0f * ab[c]; }
    const float padf = s_padf;

    float segA[CC];
    float intA[CC];
    #pragma unroll
    for (int c = 0; c < CC; ++c) { segA[c] = 0.0f; intA[c] = 0.0f; }
    float ceA = 0.0f;

    const int S4 = SS / 4;
    const float4* base = (const float4*)(net + (size_t)b * CC * SS);
    const uchar4* lab4 = (const uchar4*)labels + (size_t)b * S4;

    for (int it = 0; it < GPT; ++it) {
        const int g = blk * (THREADS * GPT) + it * THREADS + tid;
        float4 v[CC];
        #pragma unroll
        for (int c = 0; c < CC; ++c) v[c] = base[(size_t)c * S4 + g];
        const uchar4 L = lab4[g];

        #pragma unroll
        for (int j = 0; j < 4; ++j) {
            const int lab = u4c(L, j);
            float m[CC];
            m[0] = f4c(v[0], j);
            float fold = 0.0f;
            #pragma unroll
            for (int c = 1; c < CC; ++c) {
                const float x = f4c(v[c], j);
                m[c] = x;
                fold = fmaf(ab[c], x, fold);    // absent foreground -> bg
            }
            m[0] += fold;

            // e[c] = present ? exp(m[c]) : 0   (bias -2048 underflows exp2 to 0)
            float e[CC];
            float se = padf;                    // zero-logit padding: exp(0)*pad
            #pragma unroll
            for (int c = 0; c < CC; ++c) {
                e[c] = __builtin_amdgcn_exp2f(fmaf(m[c], L2E, bias[c]));
                se += e[c];
            }
            const float lse = LN2 * __builtin_amdgcn_logf(se);

            const float sp = se - padf;         // present-only sum (softmax denom)
            float inv = __builtin_amdgcn_rcpf(sp);
            inv = inv * (2.0f - sp * inv);      // 1 Newton step

            float mlab = 0.0f;
            #pragma unroll
            for (int c = 0; c < CC; ++c) {
                const float p = e[c] * inv;
                segA[c] += p;
                const bool isl = (lab == c);
                intA[c] += isl ? p : 0.0f;
                mlab     = isl ? m[c] : mlab;
            }
            ceA += lse - mlab;
        }
    }

    // wave-level reduction (64 lanes) then LDS accumulation
    #pragma unroll
    for (int off = 32; off > 0; off >>= 1) {
        #pragma unroll
        for (int c = 0; c < CC; ++c) {
            segA[c] += __shfl_down(segA[c], off, 64);
            intA[c] += __shfl_down(intA[c], off, 64);
        }
        ceA += __shfl_down(ceA, off, 64);
    }
    if ((tid & 63) == 0) {
        #pragma unroll
        for (int c = 0; c < CC; ++c) {
            atomicAdd(&s_red[c],      segA[c]);
            atomicAdd(&s_red[CC + c], intA[c]);
        }
        atomicAdd(&s_red[2 * CC], ceA);
    }
    __syncthreads();
    // per-block partials: disjoint addresses, plain stores (no contention)
    if (tid < 2 * CC + 1) part[tid * NBLOCKS + blockIdx.x] = s_red[tid];
}

__global__ __launch_bounds__(512)
void finalize(const unsigned int* __restrict__ counts,
              const float* __restrict__ part,
              float* __restrict__ out) {
    __shared__ float sred[2 * CC + 1][2];
    const int tid = threadIdx.x;
    const int w = tid >> 6, lane = tid & 63;
    for (int q = w; q < 2 * CC + 1; q += 8) {
        float a0 = 0.0f, a1 = 0.0f;
        const float* col = part + q * NBLOCKS;
        #pragma unroll
        for (int k = 0; k < NBLOCKS / 64; ++k) {
            const int blk = lane + (k << 6);
            const float v = col[blk];
            if (blk < BLOCKS_PER_SAMPLE) a0 += v; else a1 += v;
        }
        #pragma unroll
        for (int off = 32; off > 0; off >>= 1) {
            a0 += __shfl_down(a0, off, 64);
            a1 += __shfl_down(a1, off, 64);
        }
        if (lane == 0) { sred[q][0] = a0; sred[q][1] = a1; }
    }
    __syncthreads();
    if (tid == 0) {
        const float ce = (sred[2 * CC][0] + sred[2 * CC][1]) / (float)NVOX;
        float dc = 0.0f;
        for (int b = 0; b < BB; ++b) {
            int nb = 0;
            float acc = 0.0f;
            for (int c = 0; c < CC; ++c) {
                const unsigned int cnt = counts[b * CC + c];
                if (cnt > 0u) {
                    ++nb;
                    const float R = (float)cnt;
                    const float Sg = sred[c][b];
                    const float I  = sred[CC + c][b];
                    acc += 2.0f * I / (R + Sg + 1e-5f);
                }
            }
            dc += 1.0f - acc / (float)nb;
        }
        dc /= (float)BB;
        out[0] = 0.5f * ce + 0.5f * dc;
    }
}

extern "C" void kernel_launch(void* const* d_in, const int* in_sizes, int n_in,
                              void* d_out, int out_size, void* d_ws, size_t ws_size,
                              hipStream_t stream) {
    const float* net = (const float*)d_in[0];
    const float* tgt = (const float*)d_in[1];
    float* out = (float*)d_out;

    // workspace layout (every slot fully written by its producer — no memset)
    unsigned int* counts   = (unsigned int*)d_ws;                          // 16 u32   @0
    float*        fpar     = (float*)((char*)d_ws + 64);                   // 18 f32   @64
    unsigned int* cnt_part = (unsigned int*)((char*)d_ws + 256);           // 8*1600   @256    (51200 B)
    float*        part     = (float*)((char*)d_ws + 256 + 51200);          // 17*1600  @51456  (108800 B)
    unsigned char* labels  = (unsigned char*)d_ws + 256 + 51200 + 108800;  // NVOX B   @160256

    pass_label<<<NBLOCKS, THREADS, 0, stream>>>(tgt, labels, cnt_part);
    reduce_counts<<<1, 512, 0, stream>>>(cnt_part, counts, fpar);
    pass_main<<<NBLOCKS, THREADS, 0, stream>>>(net, labels, fpar, part);
    finalize<<<1, 512, 0, stream>>>(counts, part, out);
}